// Round 1
// baseline (1799.234 us; speedup 1.0000x reference)
//
#include <hip/hip_runtime.h>
#include <cstdint>
#include <cstddef>

// Problem constants
#define NEXP 8
#define NTOK 8192           // B*S = 4*2048
#define DMODEL 1024
#define DFFN 4096
#define CAP 17408           // 16384 assignments + 8*128 padding capacity

typedef __bf16 bf16;
typedef bf16 bf16x8 __attribute__((ext_vector_type(8)));
typedef float f32x4 __attribute__((ext_vector_type(4)));

// ---------------- workspace layout (bytes) ----------------
static constexpr size_t OFF_HDR  = 0;                       // 64 ints: [0..8)cnt [8..16)fill [16..24)off [24..32)padded
static constexpr size_t OFF_CNTH = 4096;                    // int[2048*8] per-block assignment hist
static constexpr size_t OFF_AMH  = OFF_CNTH + 65536;        // int[2048*8] per-block argmax hist
static constexpr size_t OFF_PSH  = OFF_AMH + 65536;         // float[2048*8] per-block prob sums
static constexpr size_t OFF_TOKE = OFF_PSH + 65536;         // int[2*NTOK] expert ids
static constexpr size_t OFF_TOKG = OFF_TOKE + 65536;        // float[2*NTOK] gate weights
static constexpr size_t OFF_TOKS = OFF_TOKG + 65536;        // int[2*NTOK] slots
static constexpr size_t OFF_XG   = OFF_TOKS + 65536;        // bf16[CAP*DMODEL]
static constexpr size_t OFF_W1B  = OFF_XG  + (size_t)CAP * DMODEL * 2;
static constexpr size_t OFF_W2B  = OFF_W1B + (size_t)NEXP * DFFN * DMODEL * 2;
static constexpr size_t OFF_H    = OFF_W2B + (size_t)NEXP * DMODEL * DFFN * 2;
static constexpr size_t OFF_O    = OFF_H   + (size_t)CAP * DFFN * 2;

// ---------------- small kernels ----------------

__global__ void k_zero16(uint4* __restrict__ p) {
    p[(size_t)blockIdx.x * 256 + threadIdx.x] = make_uint4(0u, 0u, 0u, 0u);
}

__global__ void k_cvt(const float* __restrict__ s, bf16* __restrict__ d, int n8) {
    int i = blockIdx.x * 256 + threadIdx.x;
    if (i >= n8) return;
    const float4* sp = (const float4*)s;
    float4 a = sp[2 * i], b = sp[2 * i + 1];
    bf16x8 pk;
    pk[0] = (bf16)a.x; pk[1] = (bf16)a.y; pk[2] = (bf16)a.z; pk[3] = (bf16)a.w;
    pk[4] = (bf16)b.x; pk[5] = (bf16)b.y; pk[6] = (bf16)b.z; pk[7] = (bf16)b.w;
    ((bf16x8*)d)[i] = pk;
}

// wave-per-token gating: fp32 logits, top-2, full softmax partials, argmax hist
__global__ void k_gate(const float* __restrict__ x, const float* __restrict__ gwt,
                       int* __restrict__ cnth, int* __restrict__ amh, float* __restrict__ psh,
                       int* __restrict__ toke, float* __restrict__ tokg) {
    int tid = threadIdx.x, w = tid >> 6, lane = tid & 63;
    int t = blockIdx.x * 4 + w;
    __shared__ int s_cnt[8]; __shared__ int s_am[8]; __shared__ float s_ps[8];
    if (tid < 8) { s_cnt[tid] = 0; s_am[tid] = 0; s_ps[tid] = 0.f; }
    __syncthreads();
    float acc[8] = {0.f,0.f,0.f,0.f,0.f,0.f,0.f,0.f};
    const float4* xr = (const float4*)(x + (size_t)t * DMODEL);
#pragma unroll
    for (int c = 0; c < 4; c++) {
        float4 xv = xr[c * 64 + lane];
#pragma unroll
        for (int e = 0; e < 8; e++) {
            float4 wv = ((const float4*)(gwt + e * DMODEL))[c * 64 + lane];
            acc[e] = fmaf(xv.x, wv.x, fmaf(xv.y, wv.y, fmaf(xv.z, wv.z, fmaf(xv.w, wv.w, acc[e]))));
        }
    }
#pragma unroll
    for (int o = 32; o; o >>= 1) {
#pragma unroll
        for (int e = 0; e < 8; e++) acc[e] += __shfl_xor(acc[e], o);
    }
    if (lane == 0) {
        int i0 = 0; float v0 = acc[0];
#pragma unroll
        for (int e = 1; e < 8; e++) if (acc[e] > v0) { v0 = acc[e]; i0 = e; }
        int i1 = -1; float v1 = -1e30f;
#pragma unroll
        for (int e = 0; e < 8; e++) if (e != i0 && acc[e] > v1) { v1 = acc[e]; i1 = e; }
        float ex = expf(v1 - v0);
        float g0 = 1.f / (1.f + ex);
        float g1 = ex / (1.f + ex);
        toke[2 * t] = i0; toke[2 * t + 1] = i1;
        tokg[2 * t] = g0; tokg[2 * t + 1] = g1;
        atomicAdd(&s_cnt[i0], 1); atomicAdd(&s_cnt[i1], 1); atomicAdd(&s_am[i0], 1);
        float p[8], sum = 0.f;
#pragma unroll
        for (int e = 0; e < 8; e++) { p[e] = expf(acc[e] - v0); sum += p[e]; }
        float inv = 1.f / sum;
#pragma unroll
        for (int e = 0; e < 8; e++) atomicAdd(&s_ps[e], p[e] * inv);
    }
    __syncthreads();
    if (tid < 8) {
        cnth[blockIdx.x * 8 + tid] = s_cnt[tid];
        amh[blockIdx.x * 8 + tid]  = s_am[tid];
        psh[blockIdx.x * 8 + tid]  = s_ps[tid];
    }
}

// single block: reduce hists -> counts, prefix offsets (padded to 128), fill=0, lb_loss
__global__ void k_offsets(const int* __restrict__ cnth, const int* __restrict__ amh,
                          const float* __restrict__ psh, int* __restrict__ hdr,
                          float* __restrict__ lb_out) {
    __shared__ int sc[8][256];
    __shared__ int sa[8][256];
    __shared__ float sp[8][256];
    int tid = threadIdx.x;
    int lc[8] = {0,0,0,0,0,0,0,0}, la[8] = {0,0,0,0,0,0,0,0};
    float lp[8] = {0.f,0.f,0.f,0.f,0.f,0.f,0.f,0.f};
    for (int b = tid; b < 2048; b += 256) {
#pragma unroll
        for (int e = 0; e < 8; e++) { lc[e] += cnth[b * 8 + e]; la[e] += amh[b * 8 + e]; lp[e] += psh[b * 8 + e]; }
    }
#pragma unroll
    for (int e = 0; e < 8; e++) { sc[e][tid] = lc[e]; sa[e][tid] = la[e]; sp[e][tid] = lp[e]; }
    __syncthreads();
    for (int s = 128; s > 0; s >>= 1) {
        if (tid < s) {
#pragma unroll
            for (int e = 0; e < 8; e++) { sc[e][tid] += sc[e][tid + s]; sa[e][tid] += sa[e][tid + s]; sp[e][tid] += sp[e][tid + s]; }
        }
        __syncthreads();
    }
    if (tid == 0) {
        int run = 0; float lb = 0.f;
        for (int e = 0; e < 8; e++) {
            int c = sc[e][0];
            hdr[e] = c;            // count
            hdr[8 + e] = 0;        // fill
            hdr[16 + e] = run;     // offset
            int pad = ((c + 127) >> 7) << 7;
            hdr[24 + e] = pad;     // padded count
            run += pad;
            lb += ((float)sa[e][0] / (float)NTOK) * (sp[e][0] / (float)NTOK);
        }
        lb_out[0] = 8.f * lb;
    }
}

// wave-per-token: claim slots, gather x row into per-expert bf16 buffers
__global__ void k_scatter(const float* __restrict__ x, int* __restrict__ hdr,
                          const int* __restrict__ toke, int* __restrict__ toks,
                          bf16* __restrict__ Xg) {
    int tid = threadIdx.x, w = tid >> 6, lane = tid & 63;
    int t = blockIdx.x * 4 + w;
    int s0 = 0, s1 = 0;
    if (lane == 0) {
        int e0 = toke[2 * t], e1 = toke[2 * t + 1];
        s0 = hdr[16 + e0] + atomicAdd(&hdr[8 + e0], 1);
        s1 = hdr[16 + e1] + atomicAdd(&hdr[8 + e1], 1);
        toks[2 * t] = s0; toks[2 * t + 1] = s1;
    }
    s0 = __shfl(s0, 0); s1 = __shfl(s1, 0);
    const float4* xr = (const float4*)(x + (size_t)t * DMODEL);
    bf16* d0 = Xg + (size_t)s0 * DMODEL;
    bf16* d1 = Xg + (size_t)s1 * DMODEL;
#pragma unroll
    for (int c = 0; c < 2; c++) {
        int base = c * 512 + lane * 8;
        float4 u = xr[base >> 2], v = xr[(base >> 2) + 1];
        bf16x8 pk;
        pk[0] = (bf16)u.x; pk[1] = (bf16)u.y; pk[2] = (bf16)u.z; pk[3] = (bf16)u.w;
        pk[4] = (bf16)v.x; pk[5] = (bf16)v.y; pk[6] = (bf16)v.z; pk[7] = (bf16)v.w;
        *(bf16x8*)(d0 + base) = pk;
        *(bf16x8*)(d1 + base) = pk;
    }
}

// ---------------- grouped MFMA GEMM (m97 recipe) ----------------
__device__ __forceinline__ void gll16(const bf16* g, bf16* l) {
    __builtin_amdgcn_global_load_lds((const __attribute__((address_space(1))) unsigned int*)g,
                                     (__attribute__((address_space(3))) unsigned int*)l, 16, 0, 0);
}

__device__ __forceinline__ float gelu_exact(float v) {
    return 0.5f * v * (1.0f + erff(v * 0.70710678118654752f));
}

// C[M,ND] = A[M,KD] @ W[ND,KD]^T + bias  (per expert, M = padded token count)
// GELU_BF16: apply exact gelu, store bf16 (GEMM1 -> H); else store f32 (GEMM2 -> O)
template <int KD, int ND, bool GELU_BF16>
__global__ __launch_bounds__(256) void k_gemm(
    const bf16* __restrict__ Abase, const bf16* __restrict__ Wbase,
    const float* __restrict__ bias, void* __restrict__ Cbase,
    const int* __restrict__ hdr) {
    int e = blockIdx.z;
    int padded = hdr[24 + e];
    int mt = blockIdx.y;
    if (mt * 128 >= padded) return;
    int row0 = hdr[16 + e] + mt * 128;
    int nt = blockIdx.x * 128;

    const bf16* A = Abase + (size_t)row0 * KD;
    const bf16* W = Wbase + (size_t)e * ND * KD + (size_t)nt * KD;

    __shared__ bf16 As[128 * 64];
    __shared__ bf16 Bs[128 * 64];

    int tid = threadIdx.x, w = tid >> 6, lane = tid & 63;
    int lrow = lane >> 3;            // 0..7 within 8-row staging group
    int lcol = (lane & 7) * 8;       // element offset within 64-wide k-slab
    int wm = (w & 1) * 64, wn = (w >> 1) * 64;
    int fr = lane & 15, quad = lane >> 4;

    f32x4 acc[4][4] = {};

    for (int k0 = 0; k0 < KD; k0 += 64) {
#pragma unroll
        for (int i = 0; i < 4; i++) {
            int rb = w * 32 + i * 8;
            gll16(A + (size_t)(rb + lrow) * KD + k0 + lcol, &As[rb * 64]);
            gll16(W + (size_t)(rb + lrow) * KD + k0 + lcol, &Bs[rb * 64]);
        }
        __syncthreads();
#pragma unroll
        for (int kk = 0; kk < 64; kk += 32) {
            bf16x8 af[4], bfr[4];
#pragma unroll
            for (int i = 0; i < 4; i++) af[i]  = *(const bf16x8*)&As[(wm + i * 16 + fr) * 64 + kk + quad * 8];
#pragma unroll
            for (int j = 0; j < 4; j++) bfr[j] = *(const bf16x8*)&Bs[(wn + j * 16 + fr) * 64 + kk + quad * 8];
#pragma unroll
            for (int i = 0; i < 4; i++)
#pragma unroll
                for (int j = 0; j < 4; j++)
                    acc[i][j] = __builtin_amdgcn_mfma_f32_16x16x32_bf16(af[i], bfr[j], acc[i][j], 0, 0, 0);
        }
        __syncthreads();
    }

    // epilogue: C/D layout col=lane&15, row=quad*4+reg  [verified m89/m91]
#pragma unroll
    for (int j = 0; j < 4; j++) {
        int col = nt + wn + j * 16 + fr;
        float bv = bias[e * ND + col];
#pragma unroll
        for (int i = 0; i < 4; i++) {
#pragma unroll
            for (int r = 0; r < 4; r++) {
                int row = row0 + wm + i * 16 + quad * 4 + r;
                float v = acc[i][j][r] + bv;
                if (GELU_BF16) {
                    v = gelu_exact(v);
                    ((bf16*)Cbase)[(size_t)row * ND + col] = (bf16)v;
                } else {
                    ((float*)Cbase)[(size_t)row * ND + col] = v;
                }
            }
        }
    }
}

// out[t] = g0*O[s0] + g1*O[s1]   (O already includes +b2)
__global__ void k_combine(const float* __restrict__ O, const int* __restrict__ toks,
                          const float* __restrict__ tokg, float* __restrict__ out) {
    int t = blockIdx.x;
    int s0 = toks[2 * t], s1 = toks[2 * t + 1];
    float g0 = tokg[2 * t], g1 = tokg[2 * t + 1];
    const float4* o0 = (const float4*)(O + (size_t)s0 * DMODEL);
    const float4* o1 = (const float4*)(O + (size_t)s1 * DMODEL);
    float4* dst = (float4*)(out + (size_t)t * DMODEL);
    int i = threadIdx.x;
    float4 a = o0[i], b = o1[i];
    float4 r;
    r.x = g0 * a.x + g1 * b.x;
    r.y = g0 * a.y + g1 * b.y;
    r.z = g0 * a.z + g1 * b.z;
    r.w = g0 * a.w + g1 * b.w;
    dst[i] = r;
}

// ---------------- launch ----------------
extern "C" void kernel_launch(void* const* d_in, const int* in_sizes, int n_in,
                              void* d_out, int out_size, void* d_ws, size_t ws_size,
                              hipStream_t stream) {
    const float* x   = (const float*)d_in[0];
    const float* gwt = (const float*)d_in[1];
    const float* w1  = (const float*)d_in[2];
    const float* b1  = (const float*)d_in[3];
    const float* w2  = (const float*)d_in[4];
    const float* b2  = (const float*)d_in[5];
    float* out = (float*)d_out;

    char* ws = (char*)d_ws;
    int*   hdr  = (int*)(ws + OFF_HDR);
    int*   cnth = (int*)(ws + OFF_CNTH);
    int*   amh  = (int*)(ws + OFF_AMH);
    float* psh  = (float*)(ws + OFF_PSH);
    int*   toke = (int*)(ws + OFF_TOKE);
    float* tokg = (float*)(ws + OFF_TOKG);
    int*   toks = (int*)(ws + OFF_TOKS);
    bf16*  Xg   = (bf16*)(ws + OFF_XG);
    bf16*  w1b  = (bf16*)(ws + OFF_W1B);
    bf16*  w2b  = (bf16*)(ws + OFF_W2B);
    bf16*  H    = (bf16*)(ws + OFF_H);
    float* O    = (float*)(ws + OFF_O);

    // zero Xg (covers padding rows): CAP*DMODEL*2 bytes / 4096 per block = 8704 blocks
    k_zero16<<<8704, 256, 0, stream>>>((uint4*)(ws + OFF_XG));
    // convert weights to bf16 (each 33,554,432 elems -> 4,194,304 x8-chunks)
    k_cvt<<<16384, 256, 0, stream>>>(w1, w1b, 4194304);
    k_cvt<<<16384, 256, 0, stream>>>(w2, w2b, 4194304);
    // gating
    k_gate<<<2048, 256, 0, stream>>>(x, gwt, cnth, amh, psh, toke, tokg);
    // offsets + lb_loss (written at out[NTOK*DMODEL])
    k_offsets<<<1, 256, 0, stream>>>(cnth, amh, psh, hdr, out + (size_t)NTOK * DMODEL);
    // scatter tokens
    k_scatter<<<2048, 256, 0, stream>>>(x, hdr, toke, toks, Xg);
    // GEMM1: H = gelu(Xg @ w1^T + b1)   [M x 4096], K=1024
    dim3 g1(DFFN / 128, 64, NEXP);
    k_gemm<DMODEL, DFFN, true><<<g1, 256, 0, stream>>>(Xg, w1b, b1, (void*)H, hdr);
    // GEMM2: O = H @ w2^T + b2          [M x 1024], K=4096
    dim3 g2(DMODEL / 128, 64, NEXP);
    k_gemm<DFFN, DMODEL, false><<<g2, 256, 0, stream>>>(H, w2b, b2, (void*)O, hdr);
    // combine
    k_combine<<<NTOK, 256, 0, stream>>>(O, toks, tokg, out);
}

// Round 2
// 1010.441 us; speedup vs baseline: 1.7806x; 1.7806x over previous
//
#include <hip/hip_runtime.h>
#include <cstdint>
#include <cstddef>

// Problem constants
#define NEXP 8
#define NTOK 8192           // B*S = 4*2048
#define DMODEL 1024
#define DFFN 4096
#define CAP 17408           // 16384 assignments + 8*128 padding capacity

typedef __bf16 bf16;
typedef bf16 bf16x8 __attribute__((ext_vector_type(8)));
typedef float f32x4 __attribute__((ext_vector_type(4)));

// ---------------- workspace layout (bytes) ----------------
static constexpr size_t OFF_HDR  = 0;                       // 64 ints: [0..8)cnt [16..24)off [24..32)padded
static constexpr size_t OFF_CNTH = 4096;                    // int[2048*8] per-block assignment hist
static constexpr size_t OFF_AMH  = OFF_CNTH + 65536;        // int[2048*8] per-block argmax hist
static constexpr size_t OFF_PSH  = OFF_AMH + 65536;         // float[2048*8] per-block prob sums
static constexpr size_t OFF_TOKE = OFF_PSH + 65536;         // int[2*NTOK] expert ids
static constexpr size_t OFF_TOKG = OFF_TOKE + 65536;        // float[2*NTOK] gate weights
static constexpr size_t OFF_TOKS = OFF_TOKG + 65536;        // int[2*NTOK] slots
static constexpr size_t OFF_BB   = OFF_TOKS + 65536;        // int[2048*8] per-block slot bases
static constexpr size_t OFF_XG   = OFF_BB + 65536;          // bf16[CAP*DMODEL]
static constexpr size_t OFF_W1B  = OFF_XG  + (size_t)CAP * DMODEL * 2;
static constexpr size_t OFF_W2B  = OFF_W1B + (size_t)NEXP * DFFN * DMODEL * 2;
static constexpr size_t OFF_H    = OFF_W2B + (size_t)NEXP * DMODEL * DFFN * 2;
static constexpr size_t OFF_O    = OFF_H   + (size_t)CAP * DFFN * 2;

// ---------------- small kernels ----------------

__global__ void k_zero16(uint4* __restrict__ p) {
    p[(size_t)blockIdx.x * 256 + threadIdx.x] = make_uint4(0u, 0u, 0u, 0u);
}

__global__ void k_cvt(const float* __restrict__ s, bf16* __restrict__ d, int n8) {
    int i = blockIdx.x * 256 + threadIdx.x;
    if (i >= n8) return;
    const float4* sp = (const float4*)s;
    float4 a = sp[2 * i], b = sp[2 * i + 1];
    bf16x8 pk;
    pk[0] = (bf16)a.x; pk[1] = (bf16)a.y; pk[2] = (bf16)a.z; pk[3] = (bf16)a.w;
    pk[4] = (bf16)b.x; pk[5] = (bf16)b.y; pk[6] = (bf16)b.z; pk[7] = (bf16)b.w;
    ((bf16x8*)d)[i] = pk;
}

// wave-per-token gating: fp32 logits, top-2, full softmax partials, argmax hist
__global__ void k_gate(const float* __restrict__ x, const float* __restrict__ gwt,
                       int* __restrict__ cnth, int* __restrict__ amh, float* __restrict__ psh,
                       int* __restrict__ toke, float* __restrict__ tokg) {
    int tid = threadIdx.x, w = tid >> 6, lane = tid & 63;
    int t = blockIdx.x * 4 + w;
    __shared__ int s_cnt[8]; __shared__ int s_am[8]; __shared__ float s_ps[8];
    if (tid < 8) { s_cnt[tid] = 0; s_am[tid] = 0; s_ps[tid] = 0.f; }
    __syncthreads();
    float acc[8] = {0.f,0.f,0.f,0.f,0.f,0.f,0.f,0.f};
    const float4* xr = (const float4*)(x + (size_t)t * DMODEL);
#pragma unroll
    for (int c = 0; c < 4; c++) {
        float4 xv = xr[c * 64 + lane];
#pragma unroll
        for (int e = 0; e < 8; e++) {
            float4 wv = ((const float4*)(gwt + e * DMODEL))[c * 64 + lane];
            acc[e] = fmaf(xv.x, wv.x, fmaf(xv.y, wv.y, fmaf(xv.z, wv.z, fmaf(xv.w, wv.w, acc[e]))));
        }
    }
#pragma unroll
    for (int o = 32; o; o >>= 1) {
#pragma unroll
        for (int e = 0; e < 8; e++) acc[e] += __shfl_xor(acc[e], o);
    }
    if (lane == 0) {
        int i0 = 0; float v0 = acc[0];
#pragma unroll
        for (int e = 1; e < 8; e++) if (acc[e] > v0) { v0 = acc[e]; i0 = e; }
        int i1 = -1; float v1 = -1e30f;
#pragma unroll
        for (int e = 0; e < 8; e++) if (e != i0 && acc[e] > v1) { v1 = acc[e]; i1 = e; }
        float ex = expf(v1 - v0);
        float g0 = 1.f / (1.f + ex);
        float g1 = ex / (1.f + ex);
        toke[2 * t] = i0; toke[2 * t + 1] = i1;
        tokg[2 * t] = g0; tokg[2 * t + 1] = g1;
        atomicAdd(&s_cnt[i0], 1); atomicAdd(&s_cnt[i1], 1); atomicAdd(&s_am[i0], 1);
        float p[8], sum = 0.f;
#pragma unroll
        for (int e = 0; e < 8; e++) { p[e] = expf(acc[e] - v0); sum += p[e]; }
        float inv = 1.f / sum;
#pragma unroll
        for (int e = 0; e < 8; e++) atomicAdd(&s_ps[e], p[e] * inv);
    }
    __syncthreads();
    if (tid < 8) {
        cnth[blockIdx.x * 8 + tid] = s_cnt[tid];
        amh[blockIdx.x * 8 + tid]  = s_am[tid];
        psh[blockIdx.x * 8 + tid]  = s_ps[tid];
    }
}

// single block: per-gate-block exclusive slot bases (scan), expert offsets, lb_loss.
// NO atomics anywhere downstream — fully deterministic slot assignment.
__global__ void k_offsets(const int* __restrict__ cnth, const int* __restrict__ amh,
                          const float* __restrict__ psh, int* __restrict__ hdr,
                          int* __restrict__ bb, float* __restrict__ lb_out) {
    __shared__ int sc[8][256];      // scan array (thread totals -> inclusive prefix)
    __shared__ int sa[8][256];
    __shared__ float sp[8][256];
    __shared__ int sOff[8];
    int tid = threadIdx.x;
    // each thread owns 8 consecutive gate-blocks
    int tc[8] = {0,0,0,0,0,0,0,0}, la[8] = {0,0,0,0,0,0,0,0};
    float lp[8] = {0.f,0.f,0.f,0.f,0.f,0.f,0.f,0.f};
    for (int j = 0; j < 8; j++) {
        int b = tid * 8 + j;
#pragma unroll
        for (int e = 0; e < 8; e++) { tc[e] += cnth[b * 8 + e]; la[e] += amh[b * 8 + e]; lp[e] += psh[b * 8 + e]; }
    }
#pragma unroll
    for (int e = 0; e < 8; e++) { sc[e][tid] = tc[e]; sa[e][tid] = la[e]; sp[e][tid] = lp[e]; }
    __syncthreads();
    // Hillis-Steele inclusive scan over 256 threads, 8 experts
    for (int s = 1; s < 256; s <<= 1) {
        int add[8];
#pragma unroll
        for (int e = 0; e < 8; e++) add[e] = (tid >= s) ? sc[e][tid - s] : 0;
        __syncthreads();
#pragma unroll
        for (int e = 0; e < 8; e++) sc[e][tid] += add[e];
        __syncthreads();
    }
    // tree-reduce argmax hist + prob sums (for lb_loss)
    for (int s = 128; s > 0; s >>= 1) {
        if (tid < s) {
#pragma unroll
            for (int e = 0; e < 8; e++) { sa[e][tid] += sa[e][tid + s]; sp[e][tid] += sp[e][tid + s]; }
        }
        __syncthreads();
    }
    if (tid == 0) {
        int run = 0; float lb = 0.f;
        for (int e = 0; e < 8; e++) {
            int c = sc[e][255];            // total count
            hdr[e] = c;
            hdr[16 + e] = run;             // offset
            int pad = ((c + 127) >> 7) << 7;
            hdr[24 + e] = pad;             // padded count
            sOff[e] = run;
            run += pad;
            lb += ((float)sa[e][0] / (float)NTOK) * (sp[e][0] / (float)NTOK);
        }
        lb_out[0] = 8.f * lb;
    }
    __syncthreads();
    // write per-gate-block bases: exclusive prefix for this thread + running within thread
    int excl[8];
#pragma unroll
    for (int e = 0; e < 8; e++) excl[e] = sOff[e] + sc[e][tid] - tc[e];
    for (int j = 0; j < 8; j++) {
        int b = tid * 8 + j;
#pragma unroll
        for (int e = 0; e < 8; e++) {
            bb[b * 8 + e] = excl[e];
            excl[e] += cnth[b * 8 + e];
        }
    }
}

// wave-per-token: deterministic slot = blockbase + rank-within-block; gather x row (bf16)
__global__ void k_scatter(const float* __restrict__ x, const int* __restrict__ bb,
                          const int* __restrict__ toke, int* __restrict__ toks,
                          bf16* __restrict__ Xg) {
    int tid = threadIdx.x, w = tid >> 6, lane = tid & 63;
    int t = blockIdx.x * 4 + w;
    // all 8 assignments of this gate-block
    int a_e = (lane < 8) ? toke[blockIdx.x * 8 + lane] : 0;
    int e0 = __shfl(a_e, 2 * w), e1 = __shfl(a_e, 2 * w + 1);
    int r0 = 0, r1 = 0;
    for (int j = 0; j < 2 * w; j++) {
        int ej = __shfl(a_e, j);
        r0 += (ej == e0);
        r1 += (ej == e1);
    }
    int s0 = bb[blockIdx.x * 8 + e0] + r0;
    int s1 = bb[blockIdx.x * 8 + e1] + r1;
    if (lane == 0) { toks[2 * t] = s0; toks[2 * t + 1] = s1; }
    const float4* xr = (const float4*)(x + (size_t)t * DMODEL);
    bf16* d0 = Xg + (size_t)s0 * DMODEL;
    bf16* d1 = Xg + (size_t)s1 * DMODEL;
#pragma unroll
    for (int c = 0; c < 2; c++) {
        int base = c * 512 + lane * 8;
        float4 u = xr[base >> 2], v = xr[(base >> 2) + 1];
        bf16x8 pk;
        pk[0] = (bf16)u.x; pk[1] = (bf16)u.y; pk[2] = (bf16)u.z; pk[3] = (bf16)u.w;
        pk[4] = (bf16)v.x; pk[5] = (bf16)v.y; pk[6] = (bf16)v.z; pk[7] = (bf16)v.w;
        *(bf16x8*)(d0 + base) = pk;
        *(bf16x8*)(d1 + base) = pk;
    }
}

// ---------------- grouped MFMA GEMM (m97 recipe) ----------------
__device__ __forceinline__ void gll16(const bf16* g, bf16* l) {
    __builtin_amdgcn_global_load_lds((const __attribute__((address_space(1))) unsigned int*)g,
                                     (__attribute__((address_space(3))) unsigned int*)l, 16, 0, 0);
}

__device__ __forceinline__ float gelu_exact(float v) {
    return 0.5f * v * (1.0f + erff(v * 0.70710678118654752f));
}

// C[M,ND] = A[M,KD] @ W[ND,KD]^T + bias  (per expert, M = padded token count)
// GELU_BF16: apply exact gelu, store bf16 (GEMM1 -> H); else store f32 (GEMM2 -> O)
template <int KD, int ND, bool GELU_BF16>
__global__ __launch_bounds__(256) void k_gemm(
    const bf16* __restrict__ Abase, const bf16* __restrict__ Wbase,
    const float* __restrict__ bias, void* __restrict__ Cbase,
    const int* __restrict__ hdr) {
    int e = blockIdx.z;
    int padded = hdr[24 + e];
    int mt = blockIdx.y;
    if (mt * 128 >= padded) return;
    int row0 = hdr[16 + e] + mt * 128;
    int nt = blockIdx.x * 128;

    const bf16* A = Abase + (size_t)row0 * KD;
    const bf16* W = Wbase + (size_t)e * ND * KD + (size_t)nt * KD;

    __shared__ bf16 As[128 * 64];
    __shared__ bf16 Bs[128 * 64];

    int tid = threadIdx.x, w = tid >> 6, lane = tid & 63;
    int lrow = lane >> 3;            // 0..7 within 8-row staging group
    int lcol = (lane & 7) * 8;       // element offset within 64-wide k-slab
    int wm = (w & 1) * 64, wn = (w >> 1) * 64;
    int fr = lane & 15, quad = lane >> 4;

    f32x4 acc[4][4] = {};

    for (int k0 = 0; k0 < KD; k0 += 64) {
#pragma unroll
        for (int i = 0; i < 4; i++) {
            int rb = w * 32 + i * 8;
            gll16(A + (size_t)(rb + lrow) * KD + k0 + lcol, &As[rb * 64]);
            gll16(W + (size_t)(rb + lrow) * KD + k0 + lcol, &Bs[rb * 64]);
        }
        __syncthreads();
#pragma unroll
        for (int kk = 0; kk < 64; kk += 32) {
            bf16x8 af[4], bfr[4];
#pragma unroll
            for (int i = 0; i < 4; i++) af[i]  = *(const bf16x8*)&As[(wm + i * 16 + fr) * 64 + kk + quad * 8];
#pragma unroll
            for (int j = 0; j < 4; j++) bfr[j] = *(const bf16x8*)&Bs[(wn + j * 16 + fr) * 64 + kk + quad * 8];
#pragma unroll
            for (int i = 0; i < 4; i++)
#pragma unroll
                for (int j = 0; j < 4; j++)
                    acc[i][j] = __builtin_amdgcn_mfma_f32_16x16x32_bf16(af[i], bfr[j], acc[i][j], 0, 0, 0);
        }
        __syncthreads();
    }

    // epilogue: C/D layout col=lane&15, row=quad*4+reg  [verified m89/m91]
#pragma unroll
    for (int j = 0; j < 4; j++) {
        int col = nt + wn + j * 16 + fr;
        float bv = bias[e * ND + col];
#pragma unroll
        for (int i = 0; i < 4; i++) {
#pragma unroll
            for (int r = 0; r < 4; r++) {
                int row = row0 + wm + i * 16 + quad * 4 + r;
                float v = acc[i][j][r] + bv;
                if (GELU_BF16) {
                    v = gelu_exact(v);
                    ((bf16*)Cbase)[(size_t)row * ND + col] = (bf16)v;
                } else {
                    ((float*)Cbase)[(size_t)row * ND + col] = v;
                }
            }
        }
    }
}

// out[t] = g0*O[s0] + g1*O[s1]   (O already includes +b2)
__global__ void k_combine(const float* __restrict__ O, const int* __restrict__ toks,
                          const float* __restrict__ tokg, float* __restrict__ out) {
    int t = blockIdx.x;
    int s0 = toks[2 * t], s1 = toks[2 * t + 1];
    float g0 = tokg[2 * t], g1 = tokg[2 * t + 1];
    const float4* o0 = (const float4*)(O + (size_t)s0 * DMODEL);
    const float4* o1 = (const float4*)(O + (size_t)s1 * DMODEL);
    float4* dst = (float4*)(out + (size_t)t * DMODEL);
    int i = threadIdx.x;
    float4 a = o0[i], b = o1[i];
    float4 r;
    r.x = g0 * a.x + g1 * b.x;
    r.y = g0 * a.y + g1 * b.y;
    r.z = g0 * a.z + g1 * b.z;
    r.w = g0 * a.w + g1 * b.w;
    dst[i] = r;
}

// ---------------- launch ----------------
extern "C" void kernel_launch(void* const* d_in, const int* in_sizes, int n_in,
                              void* d_out, int out_size, void* d_ws, size_t ws_size,
                              hipStream_t stream) {
    const float* x   = (const float*)d_in[0];
    const float* gwt = (const float*)d_in[1];
    const float* w1  = (const float*)d_in[2];
    const float* b1  = (const float*)d_in[3];
    const float* w2  = (const float*)d_in[4];
    const float* b2  = (const float*)d_in[5];
    float* out = (float*)d_out;

    char* ws = (char*)d_ws;
    int*   hdr  = (int*)(ws + OFF_HDR);
    int*   cnth = (int*)(ws + OFF_CNTH);
    int*   amh  = (int*)(ws + OFF_AMH);
    float* psh  = (float*)(ws + OFF_PSH);
    int*   toke = (int*)(ws + OFF_TOKE);
    float* tokg = (float*)(ws + OFF_TOKG);
    int*   toks = (int*)(ws + OFF_TOKS);
    int*   bb   = (int*)(ws + OFF_BB);
    bf16*  Xg   = (bf16*)(ws + OFF_XG);
    bf16*  w1b  = (bf16*)(ws + OFF_W1B);
    bf16*  w2b  = (bf16*)(ws + OFF_W2B);
    bf16*  H    = (bf16*)(ws + OFF_H);
    float* O    = (float*)(ws + OFF_O);

    // zero Xg (covers padding rows): CAP*DMODEL*2 bytes / 4096 per block = 8704 blocks
    k_zero16<<<8704, 256, 0, stream>>>((uint4*)(ws + OFF_XG));
    // convert weights to bf16 (each 33,554,432 elems -> 4,194,304 x8-chunks)
    k_cvt<<<16384, 256, 0, stream>>>(w1, w1b, 4194304);
    k_cvt<<<16384, 256, 0, stream>>>(w2, w2b, 4194304);
    // gating
    k_gate<<<2048, 256, 0, stream>>>(x, gwt, cnth, amh, psh, toke, tokg);
    // offsets + block bases + lb_loss (written at out[NTOK*DMODEL])
    k_offsets<<<1, 256, 0, stream>>>(cnth, amh, psh, hdr, bb, out + (size_t)NTOK * DMODEL);
    // scatter tokens (atomic-free)
    k_scatter<<<2048, 256, 0, stream>>>(x, bb, toke, toks, Xg);
    // GEMM1: H = gelu(Xg @ w1^T + b1)   [M x 4096], K=1024
    dim3 g1(DFFN / 128, 64, NEXP);
    k_gemm<DMODEL, DFFN, true><<<g1, 256, 0, stream>>>(Xg, w1b, b1, (void*)H, hdr);
    // GEMM2: O = H @ w2^T + b2          [M x 1024], K=4096
    dim3 g2(DMODEL / 128, 64, NEXP);
    k_gemm<DFFN, DMODEL, false><<<g2, 256, 0, stream>>>(H, w2b, b2, (void*)O, hdr);
    // combine
    k_combine<<<NTOK, 256, 0, stream>>>(O, toks, tokg, out);
}

// Round 3
// 900.564 us; speedup vs baseline: 1.9979x; 1.1220x over previous
//
#include <hip/hip_runtime.h>
#include <cstdint>
#include <cstddef>

// Problem constants
#define NEXP 8
#define NTOK 8192           // B*S = 4*2048
#define DMODEL 1024
#define DFFN 4096
#define CAP 17408           // 16384 assignments + 8*128 padding capacity

typedef __bf16 bf16;
typedef bf16 bf16x8 __attribute__((ext_vector_type(8)));
typedef float f32x4 __attribute__((ext_vector_type(4)));

// ---------------- workspace layout (bytes) ----------------
static constexpr size_t OFF_HDR  = 0;                       // 64 ints: [0..8)cnt [16..24)off [24..32)padded
static constexpr size_t OFF_CNTH = 4096;                    // int[2048*8] per-block assignment hist
static constexpr size_t OFF_AMH  = OFF_CNTH + 65536;        // int[2048*8] per-block argmax hist
static constexpr size_t OFF_PSH  = OFF_AMH + 65536;         // float[2048*8] per-block prob sums
static constexpr size_t OFF_TOKE = OFF_PSH + 65536;         // int[2*NTOK] expert ids
static constexpr size_t OFF_TOKG = OFF_TOKE + 65536;        // float[2*NTOK] gate weights
static constexpr size_t OFF_TOKS = OFF_TOKG + 65536;        // int[2*NTOK] slots
static constexpr size_t OFF_BB   = OFF_TOKS + 65536;        // int[2048*8] per-block slot bases
static constexpr size_t OFF_XG   = OFF_BB + 65536;          // bf16[CAP*DMODEL]
static constexpr size_t OFF_W1B  = OFF_XG  + (size_t)CAP * DMODEL * 2;
static constexpr size_t OFF_W2B  = OFF_W1B + (size_t)NEXP * DFFN * DMODEL * 2;
static constexpr size_t OFF_H    = OFF_W2B + (size_t)NEXP * DMODEL * DFFN * 2;
static constexpr size_t OFF_O    = OFF_H   + (size_t)CAP * DFFN * 2;

// ---------------- small kernels ----------------

__global__ void k_zero16(uint4* __restrict__ p) {
    p[(size_t)blockIdx.x * 256 + threadIdx.x] = make_uint4(0u, 0u, 0u, 0u);
}

__global__ void k_cvt(const float* __restrict__ s, bf16* __restrict__ d, int n8) {
    int i = blockIdx.x * 256 + threadIdx.x;
    if (i >= n8) return;
    const float4* sp = (const float4*)s;
    float4 a = sp[2 * i], b = sp[2 * i + 1];
    bf16x8 pk;
    pk[0] = (bf16)a.x; pk[1] = (bf16)a.y; pk[2] = (bf16)a.z; pk[3] = (bf16)a.w;
    pk[4] = (bf16)b.x; pk[5] = (bf16)b.y; pk[6] = (bf16)b.z; pk[7] = (bf16)b.w;
    ((bf16x8*)d)[i] = pk;
}

// wave-per-token gating: fp32 logits, top-2, full softmax partials, argmax hist
__global__ void k_gate(const float* __restrict__ x, const float* __restrict__ gwt,
                       int* __restrict__ cnth, int* __restrict__ amh, float* __restrict__ psh,
                       int* __restrict__ toke, float* __restrict__ tokg) {
    int tid = threadIdx.x, w = tid >> 6, lane = tid & 63;
    int t = blockIdx.x * 4 + w;
    __shared__ int s_cnt[8]; __shared__ int s_am[8]; __shared__ float s_ps[8];
    if (tid < 8) { s_cnt[tid] = 0; s_am[tid] = 0; s_ps[tid] = 0.f; }
    __syncthreads();
    float acc[8] = {0.f,0.f,0.f,0.f,0.f,0.f,0.f,0.f};
    const float4* xr = (const float4*)(x + (size_t)t * DMODEL);
#pragma unroll
    for (int c = 0; c < 4; c++) {
        float4 xv = xr[c * 64 + lane];
#pragma unroll
        for (int e = 0; e < 8; e++) {
            float4 wv = ((const float4*)(gwt + e * DMODEL))[c * 64 + lane];
            acc[e] = fmaf(xv.x, wv.x, fmaf(xv.y, wv.y, fmaf(xv.z, wv.z, fmaf(xv.w, wv.w, acc[e]))));
        }
    }
#pragma unroll
    for (int o = 32; o; o >>= 1) {
#pragma unroll
        for (int e = 0; e < 8; e++) acc[e] += __shfl_xor(acc[e], o);
    }
    if (lane == 0) {
        int i0 = 0; float v0 = acc[0];
#pragma unroll
        for (int e = 1; e < 8; e++) if (acc[e] > v0) { v0 = acc[e]; i0 = e; }
        int i1 = -1; float v1 = -1e30f;
#pragma unroll
        for (int e = 0; e < 8; e++) if (e != i0 && acc[e] > v1) { v1 = acc[e]; i1 = e; }
        float ex = expf(v1 - v0);
        float g0 = 1.f / (1.f + ex);
        float g1 = ex / (1.f + ex);
        toke[2 * t] = i0; toke[2 * t + 1] = i1;
        tokg[2 * t] = g0; tokg[2 * t + 1] = g1;
        atomicAdd(&s_cnt[i0], 1); atomicAdd(&s_cnt[i1], 1); atomicAdd(&s_am[i0], 1);
        float p[8], sum = 0.f;
#pragma unroll
        for (int e = 0; e < 8; e++) { p[e] = expf(acc[e] - v0); sum += p[e]; }
        float inv = 1.f / sum;
#pragma unroll
        for (int e = 0; e < 8; e++) atomicAdd(&s_ps[e], p[e] * inv);
    }
    __syncthreads();
    if (tid < 8) {
        cnth[blockIdx.x * 8 + tid] = s_cnt[tid];
        amh[blockIdx.x * 8 + tid]  = s_am[tid];
        psh[blockIdx.x * 8 + tid]  = s_ps[tid];
    }
}

// single block: per-gate-block exclusive slot bases (scan), expert offsets, lb_loss.
__global__ void k_offsets(const int* __restrict__ cnth, const int* __restrict__ amh,
                          const float* __restrict__ psh, int* __restrict__ hdr,
                          int* __restrict__ bb, float* __restrict__ lb_out) {
    __shared__ int sc[8][256];
    __shared__ int sa[8][256];
    __shared__ float sp[8][256];
    __shared__ int sOff[8];
    int tid = threadIdx.x;
    int tc[8] = {0,0,0,0,0,0,0,0}, la[8] = {0,0,0,0,0,0,0,0};
    float lp[8] = {0.f,0.f,0.f,0.f,0.f,0.f,0.f,0.f};
    for (int j = 0; j < 8; j++) {
        int b = tid * 8 + j;
#pragma unroll
        for (int e = 0; e < 8; e++) { tc[e] += cnth[b * 8 + e]; la[e] += amh[b * 8 + e]; lp[e] += psh[b * 8 + e]; }
    }
#pragma unroll
    for (int e = 0; e < 8; e++) { sc[e][tid] = tc[e]; sa[e][tid] = la[e]; sp[e][tid] = lp[e]; }
    __syncthreads();
    for (int s = 1; s < 256; s <<= 1) {
        int add[8];
#pragma unroll
        for (int e = 0; e < 8; e++) add[e] = (tid >= s) ? sc[e][tid - s] : 0;
        __syncthreads();
#pragma unroll
        for (int e = 0; e < 8; e++) sc[e][tid] += add[e];
        __syncthreads();
    }
    for (int s = 128; s > 0; s >>= 1) {
        if (tid < s) {
#pragma unroll
            for (int e = 0; e < 8; e++) { sa[e][tid] += sa[e][tid + s]; sp[e][tid] += sp[e][tid + s]; }
        }
        __syncthreads();
    }
    if (tid == 0) {
        int run = 0; float lb = 0.f;
        for (int e = 0; e < 8; e++) {
            int c = sc[e][255];
            hdr[e] = c;
            hdr[16 + e] = run;
            int pad = ((c + 127) >> 7) << 7;
            hdr[24 + e] = pad;
            sOff[e] = run;
            run += pad;
            lb += ((float)sa[e][0] / (float)NTOK) * (sp[e][0] / (float)NTOK);
        }
        lb_out[0] = 8.f * lb;
    }
    __syncthreads();
    int excl[8];
#pragma unroll
    for (int e = 0; e < 8; e++) excl[e] = sOff[e] + sc[e][tid] - tc[e];
    for (int j = 0; j < 8; j++) {
        int b = tid * 8 + j;
#pragma unroll
        for (int e = 0; e < 8; e++) {
            bb[b * 8 + e] = excl[e];
            excl[e] += cnth[b * 8 + e];
        }
    }
}

// wave-per-token: deterministic slot = blockbase + rank-within-block; gather x row (bf16)
__global__ void k_scatter(const float* __restrict__ x, const int* __restrict__ bb,
                          const int* __restrict__ toke, int* __restrict__ toks,
                          bf16* __restrict__ Xg) {
    int tid = threadIdx.x, w = tid >> 6, lane = tid & 63;
    int t = blockIdx.x * 4 + w;
    int a_e = (lane < 8) ? toke[blockIdx.x * 8 + lane] : 0;
    int e0 = __shfl(a_e, 2 * w), e1 = __shfl(a_e, 2 * w + 1);
    int r0 = 0, r1 = 0;
    for (int j = 0; j < 2 * w; j++) {
        int ej = __shfl(a_e, j);
        r0 += (ej == e0);
        r1 += (ej == e1);
    }
    int s0 = bb[blockIdx.x * 8 + e0] + r0;
    int s1 = bb[blockIdx.x * 8 + e1] + r1;
    if (lane == 0) { toks[2 * t] = s0; toks[2 * t + 1] = s1; }
    const float4* xr = (const float4*)(x + (size_t)t * DMODEL);
    bf16* d0 = Xg + (size_t)s0 * DMODEL;
    bf16* d1 = Xg + (size_t)s1 * DMODEL;
#pragma unroll
    for (int c = 0; c < 2; c++) {
        int base = c * 512 + lane * 8;
        float4 u = xr[base >> 2], v = xr[(base >> 2) + 1];
        bf16x8 pk;
        pk[0] = (bf16)u.x; pk[1] = (bf16)u.y; pk[2] = (bf16)u.z; pk[3] = (bf16)u.w;
        pk[4] = (bf16)v.x; pk[5] = (bf16)v.y; pk[6] = (bf16)v.z; pk[7] = (bf16)v.w;
        *(bf16x8*)(d0 + base) = pk;
        *(bf16x8*)(d1 + base) = pk;
    }
}

// ---------------- grouped MFMA GEMM (m97 recipe + XOR bank swizzle) ----------------
__device__ __forceinline__ void gll16(const bf16* g, bf16* l) {
    __builtin_amdgcn_global_load_lds((const __attribute__((address_space(1))) unsigned int*)g,
                                     (__attribute__((address_space(3))) unsigned int*)l, 16, 0, 0);
}

// fast GELU: x * sigmoid(1.5957691*(x + 0.044715 x^3)); |err vs exact| <= ~3e-4,
// far below the bf16 quantization of H. Uses v_exp_f32 + v_rcp_f32.
__device__ __forceinline__ float gelu_fast(float x) {
    float x3 = x * x * x;
    float z = fmaf(0.0713548163f, x3, 1.5957691216f * x);
    float s = __builtin_amdgcn_rcpf(1.0f + __expf(-z));
    return x * s;
}

// C[M,ND] = A[M,KD] @ W[ND,KD]^T + bias  (per expert, M = padded token count)
// LDS layout: slot (row, cb) holds global k-chunk (cb ^ (row&7)) — spreads the
// fragment reads over all 32 banks (2 lanes/bank = free) instead of 16.
template <int KD, int ND, bool GELU_BF16>
__global__ __launch_bounds__(256) void k_gemm(
    const bf16* __restrict__ Abase, const bf16* __restrict__ Wbase,
    const float* __restrict__ bias, void* __restrict__ Cbase,
    const int* __restrict__ hdr) {
    int e = blockIdx.z;
    int padded = hdr[24 + e];
    int mt = blockIdx.y;
    if (mt * 128 >= padded) return;
    int row0 = hdr[16 + e] + mt * 128;
    int nt = blockIdx.x * 128;

    const bf16* A = Abase + (size_t)row0 * KD;
    const bf16* W = Wbase + (size_t)e * ND * KD + (size_t)nt * KD;

    __shared__ bf16 As[128 * 64];
    __shared__ bf16 Bs[128 * 64];

    int tid = threadIdx.x, w = tid >> 6, lane = tid & 63;
    int lrow = lane >> 3;                         // 0..7 within 8-row staging group
    int lcolswz = ((lane & 7) ^ lrow) * 8;        // swizzled source chunk (rb%8==0 so row&7==lrow)
    int wm = (w & 1) * 64, wn = (w >> 1) * 64;
    int fr = lane & 15, quad = lane >> 4;
    int swz = quad ^ (fr & 7);                    // fragment-read chunk xor base

    f32x4 acc[4][4] = {};

    for (int k0 = 0; k0 < KD; k0 += 64) {
#pragma unroll
        for (int i = 0; i < 4; i++) {
            int rb = w * 32 + i * 8;
            gll16(A + (size_t)(rb + lrow) * KD + k0 + lcolswz, &As[rb * 64]);
            gll16(W + (size_t)(rb + lrow) * KD + k0 + lcolswz, &Bs[rb * 64]);
        }
        __syncthreads();
#pragma unroll
        for (int kk = 0; kk < 64; kk += 32) {
            int coff = (swz ^ (kk >> 3)) * 8;     // swizzled column offset (elements)
            bf16x8 af[4], bfr[4];
#pragma unroll
            for (int i = 0; i < 4; i++) af[i]  = *(const bf16x8*)&As[(wm + i * 16 + fr) * 64 + coff];
#pragma unroll
            for (int j = 0; j < 4; j++) bfr[j] = *(const bf16x8*)&Bs[(wn + j * 16 + fr) * 64 + coff];
#pragma unroll
            for (int i = 0; i < 4; i++)
#pragma unroll
                for (int j = 0; j < 4; j++)
                    acc[i][j] = __builtin_amdgcn_mfma_f32_16x16x32_bf16(af[i], bfr[j], acc[i][j], 0, 0, 0);
        }
        __syncthreads();
    }

    // epilogue: C/D layout col=lane&15, row=quad*4+reg  [verified m89/m91]
#pragma unroll
    for (int j = 0; j < 4; j++) {
        int col = nt + wn + j * 16 + fr;
        float bv = bias[e * ND + col];
#pragma unroll
        for (int i = 0; i < 4; i++) {
#pragma unroll
            for (int r = 0; r < 4; r++) {
                int row = row0 + wm + i * 16 + quad * 4 + r;
                float v = acc[i][j][r] + bv;
                if (GELU_BF16) {
                    v = gelu_fast(v);
                    ((bf16*)Cbase)[(size_t)row * ND + col] = (bf16)v;
                } else {
                    ((float*)Cbase)[(size_t)row * ND + col] = v;
                }
            }
        }
    }
}

// out[t] = g0*O[s0] + g1*O[s1]   (O already includes +b2)
__global__ void k_combine(const float* __restrict__ O, const int* __restrict__ toks,
                          const float* __restrict__ tokg, float* __restrict__ out) {
    int t = blockIdx.x;
    int s0 = toks[2 * t], s1 = toks[2 * t + 1];
    float g0 = tokg[2 * t], g1 = tokg[2 * t + 1];
    const float4* o0 = (const float4*)(O + (size_t)s0 * DMODEL);
    const float4* o1 = (const float4*)(O + (size_t)s1 * DMODEL);
    float4* dst = (float4*)(out + (size_t)t * DMODEL);
    int i = threadIdx.x;
    float4 a = o0[i], b = o1[i];
    float4 r;
    r.x = g0 * a.x + g1 * b.x;
    r.y = g0 * a.y + g1 * b.y;
    r.z = g0 * a.z + g1 * b.z;
    r.w = g0 * a.w + g1 * b.w;
    dst[i] = r;
}

// ---------------- launch ----------------
extern "C" void kernel_launch(void* const* d_in, const int* in_sizes, int n_in,
                              void* d_out, int out_size, void* d_ws, size_t ws_size,
                              hipStream_t stream) {
    const float* x   = (const float*)d_in[0];
    const float* gwt = (const float*)d_in[1];
    const float* w1  = (const float*)d_in[2];
    const float* b1  = (const float*)d_in[3];
    const float* w2  = (const float*)d_in[4];
    const float* b2  = (const float*)d_in[5];
    float* out = (float*)d_out;

    char* ws = (char*)d_ws;
    int*   hdr  = (int*)(ws + OFF_HDR);
    int*   cnth = (int*)(ws + OFF_CNTH);
    int*   amh  = (int*)(ws + OFF_AMH);
    float* psh  = (float*)(ws + OFF_PSH);
    int*   toke = (int*)(ws + OFF_TOKE);
    float* tokg = (float*)(ws + OFF_TOKG);
    int*   toks = (int*)(ws + OFF_TOKS);
    int*   bb   = (int*)(ws + OFF_BB);
    bf16*  Xg   = (bf16*)(ws + OFF_XG);
    bf16*  w1b  = (bf16*)(ws + OFF_W1B);
    bf16*  w2b  = (bf16*)(ws + OFF_W2B);
    bf16*  H    = (bf16*)(ws + OFF_H);
    float* O    = (float*)(ws + OFF_O);

    // zero Xg (covers padding rows)
    k_zero16<<<8704, 256, 0, stream>>>((uint4*)(ws + OFF_XG));
    // convert weights to bf16
    k_cvt<<<16384, 256, 0, stream>>>(w1, w1b, 4194304);
    k_cvt<<<16384, 256, 0, stream>>>(w2, w2b, 4194304);
    // gating
    k_gate<<<2048, 256, 0, stream>>>(x, gwt, cnth, amh, psh, toke, tokg);
    // offsets + block bases + lb_loss (written at out[NTOK*DMODEL])
    k_offsets<<<1, 256, 0, stream>>>(cnth, amh, psh, hdr, bb, out + (size_t)NTOK * DMODEL);
    // scatter tokens (atomic-free)
    k_scatter<<<2048, 256, 0, stream>>>(x, bb, toke, toks, Xg);
    // GEMM1: H = gelu(Xg @ w1^T + b1)   [M x 4096], K=1024
    dim3 g1(DFFN / 128, 64, NEXP);
    k_gemm<DMODEL, DFFN, true><<<g1, 256, 0, stream>>>(Xg, w1b, b1, (void*)H, hdr);
    // GEMM2: O = H @ w2^T + b2          [M x 1024], K=4096
    dim3 g2(DMODEL / 128, 64, NEXP);
    k_gemm<DFFN, DMODEL, false><<<g2, 256, 0, stream>>>(H, w2b, b2, (void*)O, hdr);
    // combine
    k_combine<<<NTOK, 256, 0, stream>>>(O, toks, tokg, out);
}